// Round 2
// baseline (1808.641 us; speedup 1.0000x reference)
//
#include <hip/hip_runtime.h>
#include <stdint.h>
#include <stddef.h>

// ---------------------------------------------------------------------------
// InceptionResNet sparse-conv block, MI355X (gfx950).
//   N=500000 pts, C=128, K=27 neighbor offsets. Inputs/out f32 (adaptive bf16).
// R5: R4's 2-deep pipeline never materialized (VGPR=84 -> compiler sank the
// gathers to their MFMA uses). Pin the schedule with sched_barrier(0) at the
// phase boundaries, make gathers branchless (address cndmask to a 256B zero
// page in ws instead of divergent if/else), __launch_bounds__(256,2) so the
// ~170-reg double-buffer fits. Loads stay compiler-visible => minimal correct
// vmcnt insertion (prefetch survives the MFMA waits).
// ---------------------------------------------------------------------------

typedef __attribute__((ext_vector_type(8))) short bf16x8;
typedef __attribute__((ext_vector_type(4))) float f32x4;

__device__ __forceinline__ float bf2f(uint16_t u) {
  union { uint32_t i; float f; } v; v.i = ((uint32_t)u) << 16; return v.f;
}
__device__ __forceinline__ uint16_t f2bf(float f) {
  union { float f; uint32_t i; } v; v.f = f;
  return (uint16_t)((v.i + 0x7fffu + ((v.i >> 16) & 1u)) >> 16);  // RNE
}
__device__ __forceinline__ bf16x8 zero8() {
  bf16x8 z = {0, 0, 0, 0, 0, 0, 0, 0};
  return z;
}
__device__ __forceinline__ bf16x8 cvt8(const float* p) {
  f32x4 u = *(const f32x4*)p, w = *(const f32x4*)(p + 4);
  bf16x8 r;
  r[0] = (short)f2bf(u[0]); r[1] = (short)f2bf(u[1]);
  r[2] = (short)f2bf(u[2]); r[3] = (short)f2bf(u[3]);
  r[4] = (short)f2bf(w[0]); r[5] = (short)f2bf(w[1]);
  r[6] = (short)f2bf(w[2]); r[7] = (short)f2bf(w[3]);
  return r;
}

// ---------------- ws layout (bytes) ----------------
// bf16 elems [0, 199680): transposed weights
//   W00t 32x128 @0 | W02t 64x32 @4096 | W01t 27x32x32 @6144
//   W10t 27x32x128 @33792 | W11t 27x64x32 @144384
// 399360: float biasF[224] (b00@0,b01@32,b02@64,b10@128,b11@160)
// 401408: int flags[4]  [0]=mask-is-bytes, [1]=x-is-f32
// 402432: zero page (256 B bf16 zeros, for masked-gather address select)
// 524288:    hA (N x 32 bf16, 32 MB)
// 34078720:  hB (N x 32 bf16, 32 MB)
// 67633152:  xb (N x 128 bf16, 128 MB)        [if ws_size permits]
// 67633152 + N*256: nbrm (N x 27 int, 54 MB)  [if ws_size permits]
#define WS_BIASF 399360
#define WS_FLAGS 401408
#define WS_ZBUF  402432
#define WS_HA    524288
#define WS_HB    34078720
#define WS_XB    67633152

__global__ void detect_modes(const uint32_t* __restrict__ xw,
                             const uint32_t* __restrict__ mw,
                             int* __restrict__ flags,
                             uint16_t* __restrict__ zbuf) {
  __shared__ int shc[256];
  __shared__ uint32_t shm[256];
  if (threadIdx.x < 128) zbuf[threadIdx.x] = 0;   // 256 B zero page
  int c = 0;
  uint32_t mv = 0;
  for (int i = threadIdx.x; i < 4096; i += 256) {
    uint32_t e = (xw[i] >> 7) & 0xFFu;   // exponent bits of LOW uint16 half
    c += (e >= 110 && e <= 135) ? 1 : 0;
  }
  for (int i = threadIdx.x; i < 2048; i += 256) mv |= mw[i];
  shc[threadIdx.x] = c;
  shm[threadIdx.x] = mv;
  __syncthreads();
  for (int s = 128; s > 0; s >>= 1) {
    if ((int)threadIdx.x < s) {
      shc[threadIdx.x] += shc[threadIdx.x + s];
      shm[threadIdx.x] |= shm[threadIdx.x + s];
    }
    __syncthreads();
  }
  if (threadIdx.x == 0) {
    flags[0] = (shm[0] > 1u) ? 1 : 0;      // byte-packed mask
    flags[1] = (shc[0] < 2048) ? 1 : 0;    // low halves not bf16-like => f32
    flags[2] = 0;
  }
}

__global__ __launch_bounds__(256) void prep_weights(
    const void* __restrict__ W00, const void* __restrict__ W01,
    const void* __restrict__ W02, const void* __restrict__ W10,
    const void* __restrict__ W11, const void* __restrict__ b00,
    const void* __restrict__ b01, const void* __restrict__ b02,
    const void* __restrict__ b10, const void* __restrict__ b11,
    uint16_t* __restrict__ wt, float* __restrict__ biasF,
    const int* __restrict__ flags) {
  const int f32 = flags[1];
  auto rd = [&](const void* p, int i) -> float {
    return f32 ? ((const float*)p)[i] : bf2f(((const uint16_t*)p)[i]);
  };
  int i = blockIdx.x * 256 + threadIdx.x;
  if (i < 4096) {                       // W00: [128][32] -> [32][128]
    int co = i >> 7, ci = i & 127;
    wt[i] = f2bf(rd(W00, ci * 32 + co)); return;
  }
  i -= 4096;
  if (i < 2048) {                       // W02: [32][64] -> [64][32]
    int co = i >> 5, ci = i & 31;
    wt[4096 + co * 32 + ci] = f2bf(rd(W02, ci * 64 + co)); return;
  }
  i -= 2048;
  if (i < 27648) {                      // W01: [27][32][32] -> T
    int k = i >> 10, r = i & 1023, co = r >> 5, ci = r & 31;
    wt[6144 + k * 1024 + co * 32 + ci] = f2bf(rd(W01, k * 1024 + ci * 32 + co)); return;
  }
  i -= 27648;
  if (i < 110592) {                     // W10: [27][128][32] -> [27][32][128]
    int k = i >> 12, r = i & 4095, co = r >> 7, ci = r & 127;
    wt[33792 + k * 4096 + co * 128 + ci] = f2bf(rd(W10, k * 4096 + ci * 32 + co)); return;
  }
  i -= 110592;
  if (i < 55296) {                      // W11: [27][32][64] -> [27][64][32]
    int k = i >> 11, r = i & 2047, co = r >> 5, ci = r & 31;
    wt[144384 + k * 2048 + co * 32 + ci] = f2bf(rd(W11, k * 2048 + ci * 64 + co)); return;
  }
  i -= 55296;
  if (i < 224) {
    float v;
    if (i < 32)        v = rd(b00, i);
    else if (i < 64)   v = rd(b01, i - 32);
    else if (i < 128)  v = rd(b02, i - 64);
    else if (i < 160)  v = rd(b10, i - 128);
    else               v = rd(b11, i - 160);
    biasF[i] = v;
  }
}

// Pack mask into nbr sign bit: nbrm[i] = nbr[i] | (mask ? 0x80000000 : 0)
__global__ __launch_bounds__(256) void pack_nbr(
    const int* __restrict__ nbr, const uint8_t* __restrict__ mask8,
    const int* __restrict__ mask32, int* __restrict__ nbrm, int total,
    const int* __restrict__ flags) {
  int i = blockIdx.x * 256 + threadIdx.x;
  if (i >= total) return;
  const int mmode = flags[0];
  int idx = nbr[i];
  bool mk = mmode ? (mask8[i] != 0) : (mask32[i] != 0);
  nbrm[i] = mk ? (idx | (int)0x80000000) : idx;
}

template <bool FDYN>
__device__ __forceinline__ bf16x8 loadA8(const void* f, size_t elem, int xf32) {
  if (FDYN && xf32) return cvt8((const float*)f + elem);
  return *(const bf16x8*)((const uint16_t*)f + elem);
}

template <bool RELU, int ROFF>
__device__ __forceinline__ void epi_store(void* outv, const void* xr, int of32,
                                          size_t p, int col, int COUT, float v,
                                          const float* biasF) {
  v += biasF[col];
  if (RELU) v = fmaxf(v, 0.f);
  if (ROFF >= 0) {
    size_t oi = p * 128 + ROFF + col;
    if (of32) {
      float r = ((const float*)xr)[oi];
      ((float*)outv)[oi] = v + r;
    } else {
      float r = bf2f(((const uint16_t*)xr)[oi]);
      ((uint16_t*)outv)[oi] = f2bf(v + r);
    }
  } else {
    ((uint16_t*)outv)[p * COUT + col] = f2bf(v);
  }
}

// ---------------- 1x1 conv (per-point matmul), optional fused cast ----------
template <int CIN, int COUT, bool RELU, int ROFF, bool FDYN, bool CAST>
__global__ __launch_bounds__(256) void conv1_k(
    const void* __restrict__ f, const uint16_t* __restrict__ wt,
    const float* __restrict__ biasF, const void* __restrict__ xr,
    void* __restrict__ outv, int n, const int* __restrict__ flags,
    uint16_t* __restrict__ xb) {
  constexpr int S = CIN / 32;
  constexpr int T = COUT / 16;
  const int xf32 = FDYN ? flags[1] : 0;
  const int of32 = (ROFF >= 0) ? flags[1] : 0;
  const int lane = threadIdx.x & 63;
  const int wid = threadIdx.x >> 6;
  const int m = lane & 15, kg = lane >> 4;
  const int tile0 = blockIdx.x * 16 + wid * 4;

  int tb[4];
  bool rowok[4];
  size_t ab[4];
#pragma unroll
  for (int mt = 0; mt < 4; ++mt) {
    tb[mt] = (tile0 + mt) * 16;
    int row = tb[mt] + m;
    rowok[mt] = row < n;
    ab[mt] = (size_t)(rowok[mt] ? row : 0) * CIN + kg * 8;
  }

  f32x4 acc[4][T];
#pragma unroll
  for (int mt = 0; mt < 4; ++mt)
#pragma unroll
    for (int t = 0; t < T; ++t) acc[mt][t] = {0.f, 0.f, 0.f, 0.f};

#pragma unroll
  for (int s = 0; s < S; ++s) {
    bf16x8 a[4];
#pragma unroll
    for (int mt = 0; mt < 4; ++mt) {
      a[mt] = rowok[mt] ? loadA8<FDYN>(f, ab[mt] + s * 32, xf32) : zero8();
      if constexpr (CAST) {
        if (rowok[mt]) *(bf16x8*)(xb + ab[mt] + s * 32) = a[mt];
      }
    }
#pragma unroll
    for (int t = 0; t < T; ++t) {
      bf16x8 b = *(const bf16x8*)(wt + (size_t)(t * 16 + m) * CIN + s * 32 + kg * 8);
#pragma unroll
      for (int mt = 0; mt < 4; ++mt)
        acc[mt][t] = __builtin_amdgcn_mfma_f32_16x16x32_bf16(a[mt], b, acc[mt][t], 0, 0, 0);
    }
  }

#pragma unroll
  for (int mt = 0; mt < 4; ++mt) {
    if (tb[mt] >= n) continue;
#pragma unroll
    for (int t = 0; t < T; ++t) {
#pragma unroll
      for (int r = 0; r < 4; ++r) {
        int p = tb[mt] + kg * 4 + r;
        if (p >= n) continue;
        epi_store<RELU, ROFF>(outv, xr, of32, (size_t)p, t * 16 + m, COUT,
                              acc[mt][t][r], biasF);
      }
    }
  }
}

// ---------------- 3x3x3 sparse conv, pinned 2-deep pipeline -----------------
// Phase order per half-iteration (in-order vmcnt => prefetch survives):
//   LOADIDX(k+2) | LOADB(k+1) | GATHER(k+1) | SBAR | MFMA(k) | SBAR
// sched_barrier(0) pins it: without it the scheduler sinks gathers to their
// MFMA uses to save VGPRs (R4: VGPR=84, pipeline dead). Gathers are
// branchless: address = mask ? &f[idx*CIN] : zbuf (256B zero page).
template <int CIN, int COUT, int MT, bool RELU, int ROFF, bool PACKED>
__global__ __launch_bounds__(256, 2) void conv3p_k(
    const uint16_t* __restrict__ f, const int* __restrict__ nbrm,
    const uint8_t* __restrict__ mask8, const int* __restrict__ mask32,
    const uint16_t* __restrict__ wt, const float* __restrict__ biasF,
    const void* __restrict__ xr, void* __restrict__ outv, int n,
    const int* __restrict__ flags, const uint16_t* __restrict__ zbuf) {
  constexpr int S = CIN / 32;
  constexpr int T = COUT / 16;
  const int mmode = PACKED ? 0 : flags[0];
  const int of32 = (ROFF >= 0) ? flags[1] : 0;
  const int lane = threadIdx.x & 63;
  const int wid = threadIdx.x >> 6;
  const int m = lane & 15, kg = lane >> 4;
  const int tile0 = (blockIdx.x * 4 + wid) * MT;

  int tb[MT];
  bool rowok[MT];
  int nb[MT];
#pragma unroll
  for (int mt = 0; mt < MT; ++mt) {
    tb[mt] = (tile0 + mt) * 16;
    int row = tb[mt] + m;
    rowok[mt] = row < n;
    nb[mt] = (rowok[mt] ? row : 0) * 27;
  }

  f32x4 acc[MT][T];
#pragma unroll
  for (int mt = 0; mt < MT; ++mt)
#pragma unroll
    for (int t = 0; t < T; ++t) acc[mt][t] = {0.f, 0.f, 0.f, 0.f};

  const uint16_t* wb = wt + (size_t)m * CIN + (size_t)kg * 8;
  const uint16_t* zq = zbuf + (size_t)kg * 8;

  int iA[MT], iB[MT], mA[MT], mB[MT];
  bf16x8 aA[MT][S], aB[MT][S];
  bf16x8 bA[T * S], bB[T * S];

  auto LOADIDX = [&](int (&ii)[MT], int (&mm)[MT], int k) {
#pragma unroll
    for (int mt = 0; mt < MT; ++mt) {
      int off = nb[mt] + k;
      ii[mt] = nbrm[off];
      if (!PACKED) mm[mt] = mmode ? (int)mask8[off] : mask32[off];
    }
  };
  auto GATHER = [&](bf16x8 (&a)[MT][S], const int (&ii)[MT],
                    const int (&mm)[MT]) {
#pragma unroll
    for (int mt = 0; mt < MT; ++mt) {
      bool mk;
      int idx;
      if (PACKED) { mk = rowok[mt] && (ii[mt] < 0); idx = ii[mt] & 0x7fffffff; }
      else        { mk = rowok[mt] && (mm[mt] != 0); idx = ii[mt]; }
      const uint16_t* q = mk ? f + (size_t)idx * CIN + (size_t)kg * 8 : zq;
#pragma unroll
      for (int s = 0; s < S; ++s) a[mt][s] = *(const bf16x8*)(q + s * 32);
    }
  };
  auto LOADB = [&](bf16x8 (&bb)[T * S], int k) {
    const uint16_t* wk = wb + (size_t)k * COUT * CIN;
#pragma unroll
    for (int t = 0; t < T; ++t)
#pragma unroll
      for (int s = 0; s < S; ++s)
        bb[t * S + s] = *(const bf16x8*)(wk + (size_t)(t * 16) * CIN + s * 32);
  };
  auto MFMA = [&](const bf16x8 (&a)[MT][S], const bf16x8 (&bb)[T * S]) {
#pragma unroll
    for (int t = 0; t < T; ++t)
#pragma unroll
      for (int s = 0; s < S; ++s)
#pragma unroll
        for (int mt = 0; mt < MT; ++mt)
          acc[mt][t] = __builtin_amdgcn_mfma_f32_16x16x32_bf16(
              a[mt][s], bb[t * S + s], acc[mt][t], 0, 0, 0);
  };

  // Prologue: idx for k=0,1; B for k=0; gathers for k=0.
  LOADIDX(iA, mA, 0);
  LOADIDX(iB, mB, 1);
  LOADB(bA, 0);
  GATHER(aA, iA, mA);
  __builtin_amdgcn_sched_barrier(0);

#pragma unroll 1
  for (int k = 0; k < 26; k += 2) {
    LOADIDX(iA, mA, k + 2);      // idx for k+2 (k+2 <= 26 always)
    LOADB(bB, k + 1);            // B for k+1 (before the k+1 gathers!)
    GATHER(aB, iB, mB);          // gathers k+1 (idx already landed)
    __builtin_amdgcn_sched_barrier(0);
    MFMA(aA, bA);                // k — leaves aB/iA/bB in flight
    __builtin_amdgcn_sched_barrier(0);
    if (k + 3 < 27) LOADIDX(iB, mB, k + 3);
    LOADB(bA, k + 2);            // B for k+2 (before the k+2 gathers!)
    GATHER(aA, iA, mA);          // gathers k+2
    __builtin_amdgcn_sched_barrier(0);
    MFMA(aB, bB);                // k+1 — leaves aA/iB/bA in flight
    __builtin_amdgcn_sched_barrier(0);
  }
  MFMA(aA, bA);                  // k=26 tail

#pragma unroll
  for (int mt = 0; mt < MT; ++mt) {
    if (tb[mt] >= n) continue;
#pragma unroll
    for (int t = 0; t < T; ++t) {
#pragma unroll
      for (int r = 0; r < 4; ++r) {
        int p = tb[mt] + kg * 4 + r;
        if (p >= n) continue;
        epi_store<RELU, ROFF>(outv, xr, of32, (size_t)p, t * 16 + m, COUT,
                              acc[mt][t][r], biasF);
      }
    }
  }
}

// ---------------- legacy 3x3x3 conv (fallback path only) --------------------
template <int CIN, int COUT, bool RELU, int ROFF, bool FDYN>
__global__ __launch_bounds__(256) void conv3_k(
    const void* __restrict__ f, const int* __restrict__ nbr,
    const uint8_t* __restrict__ mask8, const int* __restrict__ mask32,
    const uint16_t* __restrict__ wt, const float* __restrict__ biasF,
    const void* __restrict__ xr, void* __restrict__ outv, int n,
    const int* __restrict__ flags) {
  constexpr int S = CIN / 32;
  constexpr int T = COUT / 16;
  const int mmode = flags[0];
  const int xf32 = FDYN ? flags[1] : 0;
  const int of32 = (ROFF >= 0) ? flags[1] : 0;
  const int lane = threadIdx.x & 63;
  const int wid = threadIdx.x >> 6;
  const int m = lane & 15, kg = lane >> 4;
  const int tile0 = blockIdx.x * 16 + wid * 4;

  int tb[4];
  bool rowok[4];
  size_t nb[4];
#pragma unroll
  for (int mt = 0; mt < 4; ++mt) {
    tb[mt] = (tile0 + mt) * 16;
    int row = tb[mt] + m;
    rowok[mt] = row < n;
    nb[mt] = (size_t)(rowok[mt] ? row : 0) * 27;
  }

  f32x4 acc[4][T];
#pragma unroll
  for (int mt = 0; mt < 4; ++mt)
#pragma unroll
    for (int t = 0; t < T; ++t) acc[mt][t] = {0.f, 0.f, 0.f, 0.f};

#pragma unroll 1
  for (int k = 0; k < 27; ++k) {
    bf16x8 a[4][S];
#pragma unroll
    for (int mt = 0; mt < 4; ++mt) {
      bool mk = false;
      int idx = 0;
      if (rowok[mt]) {
        size_t off = nb[mt] + k;
        idx = nbr[off];
        mk = mmode ? (mask8[off] != 0) : (mask32[off] != 0);
      }
      if (mk) {
        size_t be = (size_t)idx * CIN + kg * 8;
#pragma unroll
        for (int s = 0; s < S; ++s) a[mt][s] = loadA8<FDYN>(f, be + s * 32, xf32);
      } else {
#pragma unroll
        for (int s = 0; s < S; ++s) a[mt][s] = zero8();
      }
    }
    const uint16_t* wk = wt + (size_t)k * COUT * CIN + (size_t)m * CIN + kg * 8;
#pragma unroll
    for (int t = 0; t < T; ++t) {
#pragma unroll
      for (int s = 0; s < S; ++s) {
        bf16x8 b = *(const bf16x8*)(wk + (size_t)t * 16 * CIN + s * 32);
#pragma unroll
        for (int mt = 0; mt < 4; ++mt)
          acc[mt][t] = __builtin_amdgcn_mfma_f32_16x16x32_bf16(a[mt][s], b, acc[mt][t], 0, 0, 0);
      }
    }
  }

#pragma unroll
  for (int mt = 0; mt < 4; ++mt) {
    if (tb[mt] >= n) continue;
#pragma unroll
    for (int t = 0; t < T; ++t) {
#pragma unroll
      for (int r = 0; r < 4; ++r) {
        int p = tb[mt] + kg * 4 + r;
        if (p >= n) continue;
        epi_store<RELU, ROFF>(outv, xr, of32, (size_t)p, t * 16 + m, COUT,
                              acc[mt][t][r], biasF);
      }
    }
  }
}

extern "C" void kernel_launch(void* const* d_in, const int* in_sizes, int n_in,
                              void* d_out, int out_size, void* d_ws, size_t ws_size,
                              hipStream_t stream) {
  const void* x     = d_in[0];
  const int*  nbr   = (const int*)d_in[1];
  const uint8_t* mask8  = (const uint8_t*)d_in[2];
  const int*     mask32 = (const int*)d_in[2];

  char* ws = (char*)d_ws;
  uint16_t* wt    = (uint16_t*)ws;
  float*    biasF = (float*)(ws + WS_BIASF);
  int*      flags = (int*)(ws + WS_FLAGS);
  uint16_t* zbuf  = (uint16_t*)(ws + WS_ZBUF);
  uint16_t* hA    = (uint16_t*)(ws + WS_HA);
  uint16_t* hB    = (uint16_t*)(ws + WS_HB);
  uint16_t* xb    = (uint16_t*)(ws + WS_XB);

  const int n = in_sizes[0] / 128;
  const int tiles = (n + 15) / 16;
  const int grid = (tiles + 15) / 16;        // legacy kernels: 16 tiles/block
  const int g128 = (n + 127) / 128;          // conv3p MT=2: 128 rows/block
  const int g256 = (n + 255) / 256;          // conv3p MT=4: 256 rows/block
  const int total = n * 27;

  const bool have_xb = ws_size >= (size_t)WS_XB + (size_t)n * 256;
  const size_t nbrm_off = (size_t)WS_XB + (size_t)n * 256;
  const bool have_nbrm = have_xb && ws_size >= nbrm_off + (size_t)n * 108;
  int* nbrm = (int*)(ws + nbrm_off);

  detect_modes<<<1, 256, 0, stream>>>((const uint32_t*)d_in[0],
                                      (const uint32_t*)d_in[2], flags, zbuf);
  if (have_nbrm)
    pack_nbr<<<(total + 255) / 256, 256, 0, stream>>>(nbr, mask8, mask32, nbrm,
                                                      total, flags);
  prep_weights<<<781, 256, 0, stream>>>(d_in[3], d_in[5], d_in[7], d_in[9], d_in[11],
                                        d_in[4], d_in[6], d_in[8], d_in[10], d_in[12],
                                        wt, biasF, flags);

  if (have_xb) {
    // h0 = relu(x @ W00 + b00), fused cast x -> xb (bf16, L3-resident)
    conv1_k<128, 32, true, -1, true, true><<<grid, 256, 0, stream>>>(
        x, wt + 0, biasF + 0, nullptr, hA, n, flags, xb);
    if (have_nbrm) {
      // h0b = relu(conv3(h0, W01) + b01)
      conv3p_k<32, 32, 4, true, -1, true><<<g256, 256, 0, stream>>>(
          hA, nbrm, nullptr, nullptr, wt + 6144, biasF + 32, nullptr, hB, n, flags, zbuf);
      // h1 = relu(conv3(xb, W10) + b10)
      conv3p_k<128, 32, 2, true, -1, true><<<g128, 256, 0, stream>>>(
          xb, nbrm, nullptr, nullptr, wt + 33792, biasF + 128, nullptr, hA, n, flags, zbuf);
    } else {
      conv3p_k<32, 32, 4, true, -1, false><<<g256, 256, 0, stream>>>(
          hA, nbr, mask8, mask32, wt + 6144, biasF + 32, nullptr, hB, n, flags, zbuf);
      conv3p_k<128, 32, 2, true, -1, false><<<g128, 256, 0, stream>>>(
          xb, nbr, mask8, mask32, wt + 33792, biasF + 128, nullptr, hA, n, flags, zbuf);
    }
    // out[:, 0:64] = h0b @ W02 + b02 + x[:, 0:64]
    conv1_k<32, 64, false, 0, false, false><<<grid, 256, 0, stream>>>(
        hB, wt + 4096, biasF + 64, x, d_out, n, flags, nullptr);
    // out[:, 64:128] = conv3(h1, W11) + b11 + x[:, 64:128]
    if (have_nbrm)
      conv3p_k<32, 64, 2, false, 64, true><<<g128, 256, 0, stream>>>(
          hA, nbrm, nullptr, nullptr, wt + 144384, biasF + 160, x, d_out, n, flags, zbuf);
    else
      conv3p_k<32, 64, 2, false, 64, false><<<g128, 256, 0, stream>>>(
          hA, nbr, mask8, mask32, wt + 144384, biasF + 160, x, d_out, n, flags, zbuf);
  } else {
    // Fallback (R2 path): gather f32 x directly, legacy kernels
    conv1_k<128, 32, true, -1, true, false><<<grid, 256, 0, stream>>>(
        x, wt + 0, biasF + 0, nullptr, hA, n, flags, nullptr);
    conv3_k<32, 32, true, -1, false><<<grid, 256, 0, stream>>>(
        hA, nbr, mask8, mask32, wt + 6144, biasF + 32, nullptr, hB, n, flags);
    conv3_k<128, 32, true, -1, true><<<grid, 256, 0, stream>>>(
        x, nbr, mask8, mask32, wt + 33792, biasF + 128, nullptr, hA, n, flags);
    conv1_k<32, 64, false, 0, false, false><<<grid, 256, 0, stream>>>(
        hB, wt + 4096, biasF + 64, x, d_out, n, flags, nullptr);
    conv3_k<32, 64, false, 64, false><<<grid, 256, 0, stream>>>(
        hA, nbr, mask8, mask32, wt + 144384, biasF + 160, x, d_out, n, flags);
  }
}

// Round 3
// 1700.448 us; speedup vs baseline: 1.0636x; 1.0636x over previous
//
#include <hip/hip_runtime.h>
#include <stdint.h>
#include <stddef.h>

// ---------------------------------------------------------------------------
// InceptionResNet sparse-conv block, MI355X (gfx950).
//   N=500000 pts, C=128, K=27 neighbor offsets. Inputs/out f32 (adaptive bf16).
// R6: empirical law from R1/R4/R5 counters: each random-gather pass costs
// ~500-650us regardless of payload bytes (f32 vs bf16 equal; CIN=32 kernels
// ~= CIN=128 kernel). Time ~ #gather passes. So: FUSE passes sharing nbr:
//   fused-mid: conv3(h0,W01)->hB  +  conv3(xb,W10)->hC   (one idx resolve,
//              gather 64B h0-row and 256B xb-row together)
//   fused-out: conv1(hB@W02) + conv3(hC,W11) + residual -> full out row
// 3 gather passes -> 2. R5's sched_barrier/launch_bounds/zbuf experiments
// reverted (regressed: VGPR stayed 84, dur 627->710).
// ---------------------------------------------------------------------------

typedef __attribute__((ext_vector_type(8))) short bf16x8;
typedef __attribute__((ext_vector_type(4))) float f32x4;

__device__ __forceinline__ float bf2f(uint16_t u) {
  union { uint32_t i; float f; } v; v.i = ((uint32_t)u) << 16; return v.f;
}
__device__ __forceinline__ uint16_t f2bf(float f) {
  union { float f; uint32_t i; } v; v.f = f;
  return (uint16_t)((v.i + 0x7fffu + ((v.i >> 16) & 1u)) >> 16);  // RNE
}
__device__ __forceinline__ bf16x8 zero8() {
  bf16x8 z = {0, 0, 0, 0, 0, 0, 0, 0};
  return z;
}
__device__ __forceinline__ bf16x8 cvt8(const float* p) {
  f32x4 u = *(const f32x4*)p, w = *(const f32x4*)(p + 4);
  bf16x8 r;
  r[0] = (short)f2bf(u[0]); r[1] = (short)f2bf(u[1]);
  r[2] = (short)f2bf(u[2]); r[3] = (short)f2bf(u[3]);
  r[4] = (short)f2bf(w[0]); r[5] = (short)f2bf(w[1]);
  r[6] = (short)f2bf(w[2]); r[7] = (short)f2bf(w[3]);
  return r;
}

// ---------------- ws layout (bytes) ----------------
// bf16 elems [0, 199680): transposed weights
//   W00t 32x128 @0 | W02t 64x32 @4096 | W01t 27x32x32 @6144
//   W10t 27x32x128 @33792 | W11t 27x64x32 @144384
// 399360: float biasF[224] (b00@0,b01@32,b02@64,b10@128,b11@160)
// 401408: int flags[4]  [0]=mask-is-bytes, [1]=x-is-f32
// 524288:    hA (N x 32 bf16, 32 MB)
// 34078720:  hB (N x 32 bf16, 32 MB)
// 67633152:  xb (N x 128 bf16, 128 MB)          [if ws_size permits]
// +N*256:    nbrm (N x 27 int, 54 MB)           [if ws_size permits]
// +N*108:    hC (N x 32 bf16, 32 MB)            [if ws_size permits: fused]
#define WS_BIASF 399360
#define WS_FLAGS 401408
#define WS_HA    524288
#define WS_HB    34078720
#define WS_XB    67633152

__global__ void detect_modes(const uint32_t* __restrict__ xw,
                             const uint32_t* __restrict__ mw,
                             int* __restrict__ flags) {
  __shared__ int shc[256];
  __shared__ uint32_t shm[256];
  int c = 0;
  uint32_t mv = 0;
  for (int i = threadIdx.x; i < 4096; i += 256) {
    uint32_t e = (xw[i] >> 7) & 0xFFu;   // exponent bits of LOW uint16 half
    c += (e >= 110 && e <= 135) ? 1 : 0;
  }
  for (int i = threadIdx.x; i < 2048; i += 256) mv |= mw[i];
  shc[threadIdx.x] = c;
  shm[threadIdx.x] = mv;
  __syncthreads();
  for (int s = 128; s > 0; s >>= 1) {
    if ((int)threadIdx.x < s) {
      shc[threadIdx.x] += shc[threadIdx.x + s];
      shm[threadIdx.x] |= shm[threadIdx.x + s];
    }
    __syncthreads();
  }
  if (threadIdx.x == 0) {
    flags[0] = (shm[0] > 1u) ? 1 : 0;      // byte-packed mask
    flags[1] = (shc[0] < 2048) ? 1 : 0;    // low halves not bf16-like => f32
    flags[2] = 0;
  }
}

__global__ __launch_bounds__(256) void prep_weights(
    const void* __restrict__ W00, const void* __restrict__ W01,
    const void* __restrict__ W02, const void* __restrict__ W10,
    const void* __restrict__ W11, const void* __restrict__ b00,
    const void* __restrict__ b01, const void* __restrict__ b02,
    const void* __restrict__ b10, const void* __restrict__ b11,
    uint16_t* __restrict__ wt, float* __restrict__ biasF,
    const int* __restrict__ flags) {
  const int f32 = flags[1];
  auto rd = [&](const void* p, int i) -> float {
    return f32 ? ((const float*)p)[i] : bf2f(((const uint16_t*)p)[i]);
  };
  int i = blockIdx.x * 256 + threadIdx.x;
  if (i < 4096) {                       // W00: [128][32] -> [32][128]
    int co = i >> 7, ci = i & 127;
    wt[i] = f2bf(rd(W00, ci * 32 + co)); return;
  }
  i -= 4096;
  if (i < 2048) {                       // W02: [32][64] -> [64][32]
    int co = i >> 5, ci = i & 31;
    wt[4096 + co * 32 + ci] = f2bf(rd(W02, ci * 64 + co)); return;
  }
  i -= 2048;
  if (i < 27648) {                      // W01: [27][32][32] -> T
    int k = i >> 10, r = i & 1023, co = r >> 5, ci = r & 31;
    wt[6144 + k * 1024 + co * 32 + ci] = f2bf(rd(W01, k * 1024 + ci * 32 + co)); return;
  }
  i -= 27648;
  if (i < 110592) {                     // W10: [27][128][32] -> [27][32][128]
    int k = i >> 12, r = i & 4095, co = r >> 7, ci = r & 127;
    wt[33792 + k * 4096 + co * 128 + ci] = f2bf(rd(W10, k * 4096 + ci * 32 + co)); return;
  }
  i -= 110592;
  if (i < 55296) {                      // W11: [27][32][64] -> [27][64][32]
    int k = i >> 11, r = i & 2047, co = r >> 5, ci = r & 31;
    wt[144384 + k * 2048 + co * 32 + ci] = f2bf(rd(W11, k * 2048 + ci * 64 + co)); return;
  }
  i -= 55296;
  if (i < 224) {
    float v;
    if (i < 32)        v = rd(b00, i);
    else if (i < 64)   v = rd(b01, i - 32);
    else if (i < 128)  v = rd(b02, i - 64);
    else if (i < 160)  v = rd(b10, i - 128);
    else               v = rd(b11, i - 160);
    biasF[i] = v;
  }
}

// Pack mask into nbr sign bit: nbrm[i] = nbr[i] | (mask ? 0x80000000 : 0)
__global__ __launch_bounds__(256) void pack_nbr(
    const int* __restrict__ nbr, const uint8_t* __restrict__ mask8,
    const int* __restrict__ mask32, int* __restrict__ nbrm, int total,
    const int* __restrict__ flags) {
  int i = blockIdx.x * 256 + threadIdx.x;
  if (i >= total) return;
  const int mmode = flags[0];
  int idx = nbr[i];
  bool mk = mmode ? (mask8[i] != 0) : (mask32[i] != 0);
  nbrm[i] = mk ? (idx | (int)0x80000000) : idx;
}

template <bool FDYN>
__device__ __forceinline__ bf16x8 loadA8(const void* f, size_t elem, int xf32) {
  if (FDYN && xf32) return cvt8((const float*)f + elem);
  return *(const bf16x8*)((const uint16_t*)f + elem);
}

template <bool RELU, int ROFF>
__device__ __forceinline__ void epi_store(void* outv, const void* xr, int of32,
                                          size_t p, int col, int COUT, float v,
                                          const float* biasF) {
  v += biasF[col];
  if (RELU) v = fmaxf(v, 0.f);
  if (ROFF >= 0) {
    size_t oi = p * 128 + ROFF + col;
    if (of32) {
      float r = ((const float*)xr)[oi];
      ((float*)outv)[oi] = v + r;
    } else {
      float r = bf2f(((const uint16_t*)xr)[oi]);
      ((uint16_t*)outv)[oi] = f2bf(v + r);
    }
  } else {
    ((uint16_t*)outv)[p * COUT + col] = f2bf(v);
  }
}

// ---------------- 1x1 conv (per-point matmul), optional fused cast ----------
template <int CIN, int COUT, bool RELU, int ROFF, bool FDYN, bool CAST>
__global__ __launch_bounds__(256) void conv1_k(
    const void* __restrict__ f, const uint16_t* __restrict__ wt,
    const float* __restrict__ biasF, const void* __restrict__ xr,
    void* __restrict__ outv, int n, const int* __restrict__ flags,
    uint16_t* __restrict__ xb) {
  constexpr int S = CIN / 32;
  constexpr int T = COUT / 16;
  const int xf32 = FDYN ? flags[1] : 0;
  const int of32 = (ROFF >= 0) ? flags[1] : 0;
  const int lane = threadIdx.x & 63;
  const int wid = threadIdx.x >> 6;
  const int m = lane & 15, kg = lane >> 4;
  const int tile0 = blockIdx.x * 16 + wid * 4;

  int tb[4];
  bool rowok[4];
  size_t ab[4];
#pragma unroll
  for (int mt = 0; mt < 4; ++mt) {
    tb[mt] = (tile0 + mt) * 16;
    int row = tb[mt] + m;
    rowok[mt] = row < n;
    ab[mt] = (size_t)(rowok[mt] ? row : 0) * CIN + kg * 8;
  }

  f32x4 acc[4][T];
#pragma unroll
  for (int mt = 0; mt < 4; ++mt)
#pragma unroll
    for (int t = 0; t < T; ++t) acc[mt][t] = {0.f, 0.f, 0.f, 0.f};

#pragma unroll
  for (int s = 0; s < S; ++s) {
    bf16x8 a[4];
#pragma unroll
    for (int mt = 0; mt < 4; ++mt) {
      a[mt] = rowok[mt] ? loadA8<FDYN>(f, ab[mt] + s * 32, xf32) : zero8();
      if constexpr (CAST) {
        if (rowok[mt]) *(bf16x8*)(xb + ab[mt] + s * 32) = a[mt];
      }
    }
#pragma unroll
    for (int t = 0; t < T; ++t) {
      bf16x8 b = *(const bf16x8*)(wt + (size_t)(t * 16 + m) * CIN + s * 32 + kg * 8);
#pragma unroll
      for (int mt = 0; mt < 4; ++mt)
        acc[mt][t] = __builtin_amdgcn_mfma_f32_16x16x32_bf16(a[mt], b, acc[mt][t], 0, 0, 0);
    }
  }

#pragma unroll
  for (int mt = 0; mt < 4; ++mt) {
    if (tb[mt] >= n) continue;
#pragma unroll
    for (int t = 0; t < T; ++t) {
#pragma unroll
      for (int r = 0; r < 4; ++r) {
        int p = tb[mt] + kg * 4 + r;
        if (p >= n) continue;
        epi_store<RELU, ROFF>(outv, xr, of32, (size_t)p, t * 16 + m, COUT,
                              acc[mt][t][r], biasF);
      }
    }
  }
}

// ---------------- FUSED MID: conv3(h0,W01)->hB + conv3(xb,W10)->hC ----------
// One idx resolve per (row,k); gathers 64B h0-row AND 256B xb-row together.
// MT=2 (two 16-row tiles per wave). T=2 for both convs (COUT=32).
__global__ __launch_bounds__(256) void conv3_mid_fused(
    const uint16_t* __restrict__ h0, const uint16_t* __restrict__ xb,
    const int* __restrict__ nbrm, const uint16_t* __restrict__ w01,
    const uint16_t* __restrict__ w10, const float* __restrict__ biasF,
    uint16_t* __restrict__ hB, uint16_t* __restrict__ hC, int n) {
  const int lane = threadIdx.x & 63;
  const int wid = threadIdx.x >> 6;
  const int m = lane & 15, kg = lane >> 4;
  const int tile0 = (blockIdx.x * 4 + wid) * 2;

  int tb[2];
  bool rowok[2];
  int nb[2];
#pragma unroll
  for (int mt = 0; mt < 2; ++mt) {
    tb[mt] = (tile0 + mt) * 16;
    int row = tb[mt] + m;
    rowok[mt] = row < n;
    nb[mt] = (rowok[mt] ? row : 0) * 27;
  }

  f32x4 acc0[2][2], acc1[2][2];
#pragma unroll
  for (int mt = 0; mt < 2; ++mt)
#pragma unroll
    for (int t = 0; t < 2; ++t) {
      acc0[mt][t] = {0.f, 0.f, 0.f, 0.f};
      acc1[mt][t] = {0.f, 0.f, 0.f, 0.f};
    }

  const uint16_t* w01b = w01 + (size_t)m * 32 + kg * 8;
  const uint16_t* w10b = w10 + (size_t)m * 128 + kg * 8;

#pragma unroll 1
  for (int k = 0; k < 27; ++k) {
    bf16x8 a0[2], a1[2][4];
#pragma unroll
    for (int mt = 0; mt < 2; ++mt) {
      int ii = nbrm[nb[mt] + k];
      bool mk = rowok[mt] && (ii < 0);
      int idx = ii & 0x7fffffff;
      if (mk) {
        const uint16_t* p0 = h0 + (size_t)idx * 32 + kg * 8;
        const uint16_t* p1 = xb + (size_t)idx * 128 + kg * 8;
        a0[mt] = *(const bf16x8*)p0;
#pragma unroll
        for (int s = 0; s < 4; ++s) a1[mt][s] = *(const bf16x8*)(p1 + s * 32);
      } else {
        a0[mt] = zero8();
#pragma unroll
        for (int s = 0; s < 4; ++s) a1[mt][s] = zero8();
      }
    }
#pragma unroll
    for (int t = 0; t < 2; ++t) {
      bf16x8 b0 = *(const bf16x8*)(w01b + (size_t)k * 1024 + (size_t)t * 16 * 32);
#pragma unroll
      for (int mt = 0; mt < 2; ++mt)
        acc0[mt][t] = __builtin_amdgcn_mfma_f32_16x16x32_bf16(a0[mt], b0, acc0[mt][t], 0, 0, 0);
    }
#pragma unroll
    for (int t = 0; t < 2; ++t) {
#pragma unroll
      for (int s = 0; s < 4; ++s) {
        bf16x8 b1 = *(const bf16x8*)(w10b + (size_t)k * 4096 + (size_t)t * 16 * 128 + s * 32);
#pragma unroll
        for (int mt = 0; mt < 2; ++mt)
          acc1[mt][t] = __builtin_amdgcn_mfma_f32_16x16x32_bf16(a1[mt][s], b1, acc1[mt][t], 0, 0, 0);
      }
    }
  }

#pragma unroll
  for (int mt = 0; mt < 2; ++mt) {
    if (tb[mt] >= n) continue;
#pragma unroll
    for (int t = 0; t < 2; ++t) {
#pragma unroll
      for (int r = 0; r < 4; ++r) {
        int p = tb[mt] + kg * 4 + r;
        if (p >= n) continue;
        int col = t * 16 + m;
        float v0 = fmaxf(acc0[mt][t][r] + biasF[32 + col], 0.f);   // b01, relu
        float v1 = fmaxf(acc1[mt][t][r] + biasF[128 + col], 0.f);  // b10, relu
        hB[(size_t)p * 32 + col] = f2bf(v0);
        hC[(size_t)p * 32 + col] = f2bf(v1);
      }
    }
  }
}

// ---------------- FUSED OUT: conv1(hB@W02) + conv3(hC,W11) + residual ------
// out[:,0:64] = hB@W02 + b02 + x[:,0:64]; out[:,64:128] = conv3(hC,W11)+b11+x.
// MT=2, T=4 (COUT=64 each half).
__global__ __launch_bounds__(256) void conv3_out_fused(
    const uint16_t* __restrict__ hB, const uint16_t* __restrict__ hC,
    const int* __restrict__ nbrm, const uint16_t* __restrict__ w02,
    const uint16_t* __restrict__ w11, const float* __restrict__ biasF,
    const void* __restrict__ xr, void* __restrict__ outv, int n,
    const int* __restrict__ flags) {
  const int of32 = flags[1];
  const int lane = threadIdx.x & 63;
  const int wid = threadIdx.x >> 6;
  const int m = lane & 15, kg = lane >> 4;
  const int tile0 = (blockIdx.x * 4 + wid) * 2;

  int tb[2];
  bool rowok[2];
  int nb[2];
#pragma unroll
  for (int mt = 0; mt < 2; ++mt) {
    tb[mt] = (tile0 + mt) * 16;
    int row = tb[mt] + m;
    rowok[mt] = row < n;
    nb[mt] = (rowok[mt] ? row : 0) * 27;
  }

  f32x4 acc0[2][4], acc1[2][4];
#pragma unroll
  for (int mt = 0; mt < 2; ++mt)
#pragma unroll
    for (int t = 0; t < 4; ++t) {
      acc0[mt][t] = {0.f, 0.f, 0.f, 0.f};
      acc1[mt][t] = {0.f, 0.f, 0.f, 0.f};
    }

  // conv1 part: stream hB tile rows (consecutive), 8 MFMA
#pragma unroll
  for (int mt = 0; mt < 2; ++mt) {
    bf16x8 a = rowok[mt]
                   ? *(const bf16x8*)(hB + (size_t)(tb[mt] + m) * 32 + kg * 8)
                   : zero8();
#pragma unroll
    for (int t = 0; t < 4; ++t) {
      bf16x8 b = *(const bf16x8*)(w02 + (size_t)(t * 16 + m) * 32 + kg * 8);
      acc0[mt][t] = __builtin_amdgcn_mfma_f32_16x16x32_bf16(a, b, acc0[mt][t], 0, 0, 0);
    }
  }

  const uint16_t* w11b = w11 + (size_t)m * 32 + kg * 8;

  // conv3 part: gather hC rows
#pragma unroll 1
  for (int k = 0; k < 27; ++k) {
    bf16x8 a[2];
#pragma unroll
    for (int mt = 0; mt < 2; ++mt) {
      int ii = nbrm[nb[mt] + k];
      bool mk = rowok[mt] && (ii < 0);
      int idx = ii & 0x7fffffff;
      a[mt] = mk ? *(const bf16x8*)(hC + (size_t)idx * 32 + kg * 8) : zero8();
    }
#pragma unroll
    for (int t = 0; t < 4; ++t) {
      bf16x8 b = *(const bf16x8*)(w11b + (size_t)k * 2048 + (size_t)t * 16 * 32);
#pragma unroll
      for (int mt = 0; mt < 2; ++mt)
        acc1[mt][t] = __builtin_amdgcn_mfma_f32_16x16x32_bf16(a[mt], b, acc1[mt][t], 0, 0, 0);
    }
  }

#pragma unroll
  for (int mt = 0; mt < 2; ++mt) {
    if (tb[mt] >= n) continue;
#pragma unroll
    for (int t = 0; t < 4; ++t) {
#pragma unroll
      for (int r = 0; r < 4; ++r) {
        int p = tb[mt] + kg * 4 + r;
        if (p >= n) continue;
        int col = t * 16 + m;
        epi_store<false, 0>(outv, xr, of32, (size_t)p, col, 128,
                            acc0[mt][t][r], biasF + 64);   // b02 + x[:,0:64]
        epi_store<false, 64>(outv, xr, of32, (size_t)p, col, 128,
                             acc1[mt][t][r], biasF + 160); // b11 + x[:,64:128]
      }
    }
  }
}

// ---------------- 3x3x3 sparse conv (R4 form, fallback path) ----------------
template <int CIN, int COUT, int MT, bool RELU, int ROFF, bool PACKED>
__global__ __launch_bounds__(256) void conv3p_k(
    const uint16_t* __restrict__ f, const int* __restrict__ nbrm,
    const uint8_t* __restrict__ mask8, const int* __restrict__ mask32,
    const uint16_t* __restrict__ wt, const float* __restrict__ biasF,
    const void* __restrict__ xr, void* __restrict__ outv, int n,
    const int* __restrict__ flags) {
  constexpr int S = CIN / 32;
  constexpr int T = COUT / 16;
  const int mmode = PACKED ? 0 : flags[0];
  const int of32 = (ROFF >= 0) ? flags[1] : 0;
  const int lane = threadIdx.x & 63;
  const int wid = threadIdx.x >> 6;
  const int m = lane & 15, kg = lane >> 4;
  const int tile0 = (blockIdx.x * 4 + wid) * MT;

  int tb[MT];
  bool rowok[MT];
  int nb[MT];
#pragma unroll
  for (int mt = 0; mt < MT; ++mt) {
    tb[mt] = (tile0 + mt) * 16;
    int row = tb[mt] + m;
    rowok[mt] = row < n;
    nb[mt] = (rowok[mt] ? row : 0) * 27;
  }

  f32x4 acc[MT][T];
#pragma unroll
  for (int mt = 0; mt < MT; ++mt)
#pragma unroll
    for (int t = 0; t < T; ++t) acc[mt][t] = {0.f, 0.f, 0.f, 0.f};

  const uint16_t* wb = wt + (size_t)m * CIN + (size_t)kg * 8;

#pragma unroll 1
  for (int k = 0; k < 27; ++k) {
    bf16x8 a[MT][S];
#pragma unroll
    for (int mt = 0; mt < MT; ++mt) {
      bool mk;
      int idx;
      int ii = nbrm[nb[mt] + k];
      if (PACKED) { mk = rowok[mt] && (ii < 0); idx = ii & 0x7fffffff; }
      else {
        int mm = mmode ? (int)mask8[nb[mt] + k] : mask32[nb[mt] + k];
        mk = rowok[mt] && (mm != 0);
        idx = ii;
      }
      if (mk) {
        size_t be = (size_t)idx * CIN + (size_t)kg * 8;
#pragma unroll
        for (int s = 0; s < S; ++s) a[mt][s] = *(const bf16x8*)(f + be + s * 32);
      } else {
#pragma unroll
        for (int s = 0; s < S; ++s) a[mt][s] = zero8();
      }
    }
#pragma unroll
    for (int t = 0; t < T; ++t) {
#pragma unroll
      for (int s = 0; s < S; ++s) {
        bf16x8 b = *(const bf16x8*)(wb + (size_t)k * COUT * CIN + (size_t)t * 16 * CIN + s * 32);
#pragma unroll
        for (int mt = 0; mt < MT; ++mt)
          acc[mt][t] = __builtin_amdgcn_mfma_f32_16x16x32_bf16(a[mt][s], b, acc[mt][t], 0, 0, 0);
      }
    }
  }

#pragma unroll
  for (int mt = 0; mt < MT; ++mt) {
    if (tb[mt] >= n) continue;
#pragma unroll
    for (int t = 0; t < T; ++t) {
#pragma unroll
      for (int r = 0; r < 4; ++r) {
        int p = tb[mt] + kg * 4 + r;
        if (p >= n) continue;
        epi_store<RELU, ROFF>(outv, xr, of32, (size_t)p, t * 16 + m, COUT,
                              acc[mt][t][r], biasF);
      }
    }
  }
}

// ---------------- legacy 3x3x3 conv (no-ws fallback path) -------------------
template <int CIN, int COUT, bool RELU, int ROFF, bool FDYN>
__global__ __launch_bounds__(256) void conv3_k(
    const void* __restrict__ f, const int* __restrict__ nbr,
    const uint8_t* __restrict__ mask8, const int* __restrict__ mask32,
    const uint16_t* __restrict__ wt, const float* __restrict__ biasF,
    const void* __restrict__ xr, void* __restrict__ outv, int n,
    const int* __restrict__ flags) {
  constexpr int S = CIN / 32;
  constexpr int T = COUT / 16;
  const int mmode = flags[0];
  const int xf32 = FDYN ? flags[1] : 0;
  const int of32 = (ROFF >= 0) ? flags[1] : 0;
  const int lane = threadIdx.x & 63;
  const int wid = threadIdx.x >> 6;
  const int m = lane & 15, kg = lane >> 4;
  const int tile0 = blockIdx.x * 16 + wid * 4;

  int tb[4];
  bool rowok[4];
  size_t nb[4];
#pragma unroll
  for (int mt = 0; mt < 4; ++mt) {
    tb[mt] = (tile0 + mt) * 16;
    int row = tb[mt] + m;
    rowok[mt] = row < n;
    nb[mt] = (size_t)(rowok[mt] ? row : 0) * 27;
  }

  f32x4 acc[4][T];
#pragma unroll
  for (int mt = 0; mt < 4; ++mt)
#pragma unroll
    for (int t = 0; t < T; ++t) acc[mt][t] = {0.f, 0.f, 0.f, 0.f};

#pragma unroll 1
  for (int k = 0; k < 27; ++k) {
    bf16x8 a[4][S];
#pragma unroll
    for (int mt = 0; mt < 4; ++mt) {
      bool mk = false;
      int idx = 0;
      if (rowok[mt]) {
        size_t off = nb[mt] + k;
        idx = nbr[off];
        mk = mmode ? (mask8[off] != 0) : (mask32[off] != 0);
      }
      if (mk) {
        size_t be = (size_t)idx * CIN + kg * 8;
#pragma unroll
        for (int s = 0; s < S; ++s) a[mt][s] = loadA8<FDYN>(f, be + s * 32, xf32);
      } else {
#pragma unroll
        for (int s = 0; s < S; ++s) a[mt][s] = zero8();
      }
    }
    const uint16_t* wk = wt + (size_t)k * COUT * CIN + (size_t)m * CIN + kg * 8;
#pragma unroll
    for (int t = 0; t < T; ++t) {
#pragma unroll
      for (int s = 0; s < S; ++s) {
        bf16x8 b = *(const bf16x8*)(wk + (size_t)t * 16 * CIN + s * 32);
#pragma unroll
        for (int mt = 0; mt < 4; ++mt)
          acc[mt][t] = __builtin_amdgcn_mfma_f32_16x16x32_bf16(a[mt][s], b, acc[mt][t], 0, 0, 0);
      }
    }
  }

#pragma unroll
  for (int mt = 0; mt < 4; ++mt) {
    if (tb[mt] >= n) continue;
#pragma unroll
    for (int t = 0; t < T; ++t) {
#pragma unroll
      for (int r = 0; r < 4; ++r) {
        int p = tb[mt] + kg * 4 + r;
        if (p >= n) continue;
        epi_store<RELU, ROFF>(outv, xr, of32, (size_t)p, t * 16 + m, COUT,
                              acc[mt][t][r], biasF);
      }
    }
  }
}

extern "C" void kernel_launch(void* const* d_in, const int* in_sizes, int n_in,
                              void* d_out, int out_size, void* d_ws, size_t ws_size,
                              hipStream_t stream) {
  const void* x     = d_in[0];
  const int*  nbr   = (const int*)d_in[1];
  const uint8_t* mask8  = (const uint8_t*)d_in[2];
  const int*     mask32 = (const int*)d_in[2];

  char* ws = (char*)d_ws;
  uint16_t* wt    = (uint16_t*)ws;
  float*    biasF = (float*)(ws + WS_BIASF);
  int*      flags = (int*)(ws + WS_FLAGS);
  uint16_t* hA    = (uint16_t*)(ws + WS_HA);
  uint16_t* hB    = (uint16_t*)(ws + WS_HB);
  uint16_t* xb    = (uint16_t*)(ws + WS_XB);

  const int n = in_sizes[0] / 128;
  const int tiles = (n + 15) / 16;
  const int grid = (tiles + 15) / 16;        // legacy/conv1 kernels: 16 tiles/block
  const int g128 = (n + 127) / 128;          // MT=2 kernels: 128 rows/block
  const int g256 = (n + 255) / 256;          // MT=4 kernels: 256 rows/block
  const int total = n * 27;

  const bool have_xb = ws_size >= (size_t)WS_XB + (size_t)n * 256;
  const size_t nbrm_off = (size_t)WS_XB + (size_t)n * 256;
  const bool have_nbrm = have_xb && ws_size >= nbrm_off + (size_t)n * 108;
  const size_t hC_off = nbrm_off + (size_t)n * 108;
  const bool have_fuse = have_nbrm && ws_size >= hC_off + (size_t)n * 64;
  int* nbrm = (int*)(ws + nbrm_off);
  uint16_t* hC = (uint16_t*)(ws + hC_off);

  detect_modes<<<1, 256, 0, stream>>>((const uint32_t*)d_in[0],
                                      (const uint32_t*)d_in[2], flags);
  if (have_nbrm)
    pack_nbr<<<(total + 255) / 256, 256, 0, stream>>>(nbr, mask8, mask32, nbrm,
                                                      total, flags);
  prep_weights<<<781, 256, 0, stream>>>(d_in[3], d_in[5], d_in[7], d_in[9], d_in[11],
                                        d_in[4], d_in[6], d_in[8], d_in[10], d_in[12],
                                        wt, biasF, flags);

  if (have_fuse) {
    // h0 = relu(x @ W00 + b00), fused cast x -> xb
    conv1_k<128, 32, true, -1, true, true><<<grid, 256, 0, stream>>>(
        x, wt + 0, biasF + 0, nullptr, hA, n, flags, xb);
    // hB = relu(conv3(h0,W01)+b01), hC = relu(conv3(xb,W10)+b10)  [1 gather pass]
    conv3_mid_fused<<<g128, 256, 0, stream>>>(hA, xb, nbrm, wt + 6144,
                                              wt + 33792, biasF, hB, hC, n);
    // out = [hB@W02+b02 | conv3(hC,W11)+b11] + x                  [1 gather pass]
    conv3_out_fused<<<g128, 256, 0, stream>>>(hB, hC, nbrm, wt + 4096,
                                              wt + 144384, biasF, x, d_out, n, flags);
  } else if (have_xb) {
    conv1_k<128, 32, true, -1, true, true><<<grid, 256, 0, stream>>>(
        x, wt + 0, biasF + 0, nullptr, hA, n, flags, xb);
    if (have_nbrm) {
      conv3p_k<32, 32, 4, true, -1, true><<<g256, 256, 0, stream>>>(
          hA, nbrm, nullptr, nullptr, wt + 6144, biasF + 32, nullptr, hB, n, flags);
      conv3p_k<128, 32, 2, true, -1, true><<<g128, 256, 0, stream>>>(
          xb, nbrm, nullptr, nullptr, wt + 33792, biasF + 128, nullptr, hA, n, flags);
    } else {
      conv3p_k<32, 32, 4, true, -1, false><<<g256, 256, 0, stream>>>(
          hA, (const int*)nbr, mask8, mask32, wt + 6144, biasF + 32, nullptr, hB, n, flags);
      conv3p_k<128, 32, 2, true, -1, false><<<g128, 256, 0, stream>>>(
          xb, (const int*)nbr, mask8, mask32, wt + 33792, biasF + 128, nullptr, hA, n, flags);
    }
    conv1_k<32, 64, false, 0, false, false><<<grid, 256, 0, stream>>>(
        hB, wt + 4096, biasF + 64, x, d_out, n, flags, nullptr);
    if (have_nbrm)
      conv3p_k<32, 64, 2, false, 64, true><<<g128, 256, 0, stream>>>(
          hA, nbrm, nullptr, nullptr, wt + 144384, biasF + 160, x, d_out, n, flags);
    else
      conv3p_k<32, 64, 2, false, 64, false><<<g128, 256, 0, stream>>>(
          hA, (const int*)nbr, mask8, mask32, wt + 144384, biasF + 160, x, d_out, n, flags);
  } else {
    // Fallback: gather f32 x directly, legacy kernels
    conv1_k<128, 32, true, -1, true, false><<<grid, 256, 0, stream>>>(
        x, wt + 0, biasF + 0, nullptr, hA, n, flags, nullptr);
    conv3_k<32, 32, true, -1, false><<<grid, 256, 0, stream>>>(
        hA, nbr, mask8, mask32, wt + 6144, biasF + 32, nullptr, hB, n, flags);
    conv3_k<128, 32, true, -1, true><<<grid, 256, 0, stream>>>(
        x, nbr, mask8, mask32, wt + 33792, biasF + 128, nullptr, hA, n, flags);
    conv1_k<32, 64, false, 0, false, false><<<grid, 256, 0, stream>>>(
        hB, wt + 4096, biasF + 64, x, d_out, n, flags, nullptr);
    conv3_k<32, 64, false, 64, false><<<grid, 256, 0, stream>>>(
        hA, nbr, mask8, mask32, wt + 144384, biasF + 160, x, d_out, n, flags);
  }
}